// Round 5
// baseline (947.077 us; speedup 1.0000x reference)
//
#include <hip/hip_runtime.h>
#include <hip/hip_bf16.h>
#include <stdint.h>

#define T_NO 200
#define COS_N 17
#define SUB 32
#define T_MAX 40000
#define E_MAX 4096
#define PI_F 3.14159265358979323846f
#define HALF_PI_F 1.57079632679489662f

// ---- module-scope scratch (no dependence on d_ws / ws_size) ---------------
__device__ float g_syn_e[(size_t)T_MAX * SUB];
__device__ float g_syn_i[(size_t)T_MAX * SUB];
__device__ float g_syn_f[(size_t)T_MAX * SUB];
__device__ float g_ektT[T_NO * SUB];   // tau-major: [tau][sub]
__device__ float g_iktT[T_NO * SUB];
__device__ float g_hk[T_NO];
__device__ float g_ok[T_NO];
__device__ int   g_map_e[E_MAX];
__device__ float g_wgt_e[E_MAX];
__device__ int   g_map_i[E_MAX];
__device__ float g_wgt_i[E_MAX];
__device__ int   g_dtype;              // 0 = float32, 1 = bfloat16 (set per call)

// ---- dtype-dispatching load/store ----------------------------------------
__device__ __forceinline__ float ldx(const void* p, size_t i, int dt) {
    if (dt) return __bfloat162float(((const __hip_bfloat16*)p)[i]);
    return ((const float*)p)[i];
}
__device__ __forceinline__ void stx(void* p, size_t i, float v, int dt) {
    if (dt) ((__hip_bfloat16*)p)[i] = __float2bfloat16(v);
    else    ((float*)p)[i] = v;
}

// ---------------------------------------------------------------------------
// D0: dtype detect from S_e bit patterns. f32 spikes: words in {0, 0x3F800000}.
// bf16 spikes: pairs also yield 0x00003F80 (spike at even idx) / 0x3F803F80.
// Single block; result to g_dtype (re-written every call).
// ---------------------------------------------------------------------------
__global__ void k_detect(const unsigned int* w, int nwords)
{
    __shared__ int flag;
    if (threadIdx.x == 0) flag = 0;
    __syncthreads();
    for (int i = threadIdx.x; i < nwords; i += 256) {
        unsigned v = w[i];
        if (v == 0x00003F80u || v == 0x3F803F80u) flag = 1;
    }
    __syncthreads();
    if (threadIdx.x == 0) g_dtype = flag;
}

// ---------------------------------------------------------------------------
// D1: kernel-execution probe: fill whole output with 2.0 (overwritten by the
// real pipeline if everything works).
// ---------------------------------------------------------------------------
__global__ void k_fill(void* out, int n, float val)
{
    int dt = g_dtype;
    for (int i = blockIdx.x * 256 + threadIdx.x; i < n; i += gridDim.x * 256)
        stx(out, i, val, dt);
}

// ---------------------------------------------------------------------------
// K1: setup — column->subunit maps, e/i alpha kernels (tau-major), history
// kernel (cos basis), output kernel; writes out_filters at element 2*T.
// ---------------------------------------------------------------------------
__global__ void k_setup(
    const void* C_se, const void* C_si, const void* Tau_syn, const void* Delta_syn,
    const void* W_syn, const void* W_hist, const void* Tau_out, const void* W_out,
    void* out, int T, int E_e, int E_i)
{
    int dt = g_dtype;
    size_t fbase = 2 * (size_t)T;      // element offset of out_filters
    int tid = blockIdx.x * 256 + threadIdx.x;

    if (tid < E_e) {
        int e = tid, m = 0; float w = 0.f;
        for (int s = 0; s < SUB; ++s) {
            float c = ldx(C_se, (size_t)s * E_e + e, dt);
            if (c != 0.f) { m = s; w = c; }
        }
        g_map_e[e] = m; g_wgt_e[e] = w;
        return;
    }
    tid -= E_e;
    if (tid < E_i) {
        int e = tid, m = 0; float w = 0.f;
        for (int s = 0; s < SUB; ++s) {
            float c = ldx(C_si, (size_t)s * E_i + e, dt);
            if (c != 0.f) { m = s; w = c; }
        }
        g_map_i[e] = m; g_wgt_i[e] = w;
        return;
    }
    tid -= E_i;
    if (tid < SUB * T_NO) {            // e_kern
        int s = tid / T_NO, t = tid % T_NO;
        float delta = expf(ldx(Delta_syn, s * 2 + 0, dt));
        float tau   = expf(ldx(Tau_syn,   s * 2 + 0, dt));
        float w     = expf(ldx(W_syn,     s * 2 + 0, dt));
        float te = fmaxf((float)t - delta, 0.f) / tau;
        float v = te * expf(-te) * w;
        g_ektT[t * SUB + s] = v;
        stx(out, fbase + (size_t)s * T_NO + t, v, dt);
        return;
    }
    tid -= SUB * T_NO;
    if (tid < SUB * T_NO) {            // i_kern
        int s = tid / T_NO, t = tid % T_NO;
        float delta = expf(ldx(Delta_syn, s * 2 + 1, dt));
        float tau   = expf(ldx(Tau_syn,   s * 2 + 1, dt));
        float w     = expf(ldx(W_syn,     s * 2 + 1, dt));
        float ti = fmaxf((float)t - delta, 0.f) / tau;
        float v = -ti * expf(-ti) * w;
        g_iktT[t * SUB + s] = v;
        stx(out, fbase + (size_t)SUB * T_NO + (size_t)s * T_NO + t, v, dt);
        return;
    }
    tid -= SUB * T_NO;
    if (tid < T_NO) {                  // hist_kern = -(exp(W_hist) @ cos_basis)
        int t = tid;
        float raw = 4.0f * logf((float)t + 1.0f);
        float acc = 0.f;
        for (int n = 0; n < COS_N; ++n) {
            float phi = HALF_PI_F * (float)n;
            float d = raw - phi;
            float b = (raw >= phi - PI_F && raw <= phi + PI_F) ? (0.5f * cosf(d) + 0.5f) : 0.f;
            acc += expf(ldx(W_hist, n, dt)) * b;
        }
        float v = -acc;
        g_hk[t] = v;
        stx(out, fbase + 2 * (size_t)SUB * T_NO + t, v, dt);
        return;
    }
    tid -= T_NO;
    if (tid < T_NO) {                  // out_kern (internal only)
        float tau = expf(ldx(Tau_out, 0, dt));
        float w   = expf(ldx(W_out, 0, dt));
        float tt = (float)tid / tau;
        g_ok[tid] = tt * expf(-tt) * w;
    }
}

// ---------------------------------------------------------------------------
// K2: spike projection. One wave per time row; LDS atomicAdd into 32 buckets
// on nonzero (2% dense) entries.
// ---------------------------------------------------------------------------
__global__ void k_project(const void* Se, const void* Si, int T, int E_e, int E_i)
{
    __shared__ float bE[4 * SUB];
    __shared__ float bI[4 * SUB];
    int dt = g_dtype;
    int tid = threadIdx.x;
    if (tid < 128) bE[tid] = 0.f; else bI[tid - 128] = 0.f;
    __syncthreads();

    int wid = tid >> 6, lane = tid & 63;
    int t = blockIdx.x * 4 + wid;
    if (t < T) {
        for (int idx = lane; idx < E_e; idx += 64) {
            float v = ldx(Se, (size_t)t * E_e + idx, dt);
            if (v != 0.f) atomicAdd(&bE[wid * SUB + g_map_e[idx]], v * g_wgt_e[idx]);
        }
        for (int idx = lane; idx < E_i; idx += 64) {
            float v = ldx(Si, (size_t)t * E_i + idx, dt);
            if (v != 0.f) atomicAdd(&bI[wid * SUB + g_map_i[idx]], v * g_wgt_i[idx]);
        }
    }
    __syncthreads();
    if (t < T) {
        if (lane < SUB) g_syn_e[(size_t)t * SUB + lane] = bE[wid * SUB + lane];
        else            g_syn_i[(size_t)t * SUB + (lane - SUB)] = bI[wid * SUB + (lane - SUB)];
    }
}

// ---------------------------------------------------------------------------
// K3: depthwise causal conv (f32 scratch only). One thread per (t,s).
//   syn_f[t,s] = sum_tau ek[tau,s]*syn_e[t-1-tau,s] + ik[tau,s]*syn_i[t-1-tau,s]
// ---------------------------------------------------------------------------
__global__ void k_conv(int T)
{
    int gid = blockIdx.x * 256 + threadIdx.x;
    int s = gid & (SUB - 1);
    int t = gid >> 5;
    if (t >= T) return;
    float acc = 0.f;
    for (int tau = 0; tau < T_NO; ++tau) {
        int r = t - 1 - tau;
        if (r < 0) break;
        acc += g_ektT[tau * SUB + s] * g_syn_e[(size_t)r * SUB + s]
             + g_iktT[tau * SUB + s] * g_syn_i[(size_t)r * SUB + s];
    }
    g_syn_f[(size_t)t * SUB + s] = acc;
}

// ---------------------------------------------------------------------------
// K4: history conv on observed Z + sequential tree walk (full C_den*exp(W_sub),
// scatter form matching the ref's descending-idx loop) + heaviside step.
// Writes Z_out at element offset T of out.
// ---------------------------------------------------------------------------
__global__ void k_tree(const void* Z, const void* C_den, const void* W_sub,
                       const void* Theta, void* out, int T)
{
    __shared__ float s_hk[T_NO];
    __shared__ float s_C[SUB * SUB];   // C_den[p][k] * exp(W_sub[k])
    __shared__ float s_th[SUB];
    int dt = g_dtype;
    int tid = threadIdx.x;
    for (int i = tid; i < T_NO; i += 256) s_hk[i] = g_hk[i];
    for (int i = tid; i < SUB * SUB; i += 256) {
        int p = i >> 5, k = i & 31;
        s_C[i] = ldx(C_den, p * SUB + k, dt) * expf(ldx(W_sub, k, dt));
    }
    if (tid < SUB) s_th[tid] = ldx(Theta, tid, dt);
    __syncthreads();

    int t = blockIdx.x * 256 + tid;
    if (t >= T) return;

    float h = 0.f;                     // sum_tau hk[tau] * Z[t-1-tau]
    int nmax = (t < T_NO) ? t : T_NO;
    for (int tau = 0; tau < nmax; ++tau)
        h += s_hk[tau] * ldx(Z, t - 1 - tau, dt);

    float a[SUB];
#pragma unroll
    for (int j = 0; j < SUB; ++j) a[j] = g_syn_f[(size_t)t * SUB + j] + s_th[j];
#pragma unroll
    for (int idx = SUB - 1; idx >= 1; --idx) {
        float v = tanhf(a[idx]);
#pragma unroll
        for (int p = 0; p < SUB; ++p)
            if (p < idx) a[p] += v * s_C[p * SUB + idx];
    }
    float zin = a[0] + h;
    stx(out, (size_t)T + t, (zin > 0.f ? 1.f : 0.f), dt);   // heaviside(x,0)
}

// ---------------------------------------------------------------------------
// K5: output alpha-kernel conv of Z_out (read back from out at offset T).
// ---------------------------------------------------------------------------
__global__ void k_vout(void* out, int T)
{
    __shared__ float s_ok[T_NO];
    int dt = g_dtype;
    for (int i = threadIdx.x; i < T_NO; i += 256) s_ok[i] = g_ok[i];
    __syncthreads();
    int t = blockIdx.x * 256 + threadIdx.x;
    if (t >= T) return;
    float acc = 0.f;
    int nmax = (t < T_NO) ? t : T_NO;
    for (int tau = 0; tau < nmax; ++tau)
        acc += s_ok[tau] * ldx(out, (size_t)T + (t - 1 - tau), dt);
    stx(out, t, acc, dt);
}

// ---------------------------------------------------------------------------
struct InIdx { int S_e, S_i, Z, C_den, C_se, C_si, Tau, Del, Wsyn, Wsub, Whist, Theta, TauO, Wout; };

extern "C" void kernel_launch(void* const* d_in, const int* in_sizes, int n_in,
                              void* d_out, int out_size, void* d_ws, size_t ws_size,
                              hipStream_t stream)
{
    (void)n_in; (void)d_ws; (void)ws_size;
    size_t markbytes = (size_t)out_size * 2;   // bf16-sized: safe under either dtype

    // marker A: entered kernel_launch; memset works (error would print 5.15e+01)
    hipMemsetAsync(d_out, 0x40, markbytes, stream);
    hipMemsetAsync(d_out, 0x40, markbytes, 0);     // null stream, in case `stream` is bad

    // ---- decode in_sizes: int32 vs int64, insertion vs sorted order --------
    const InIdx LA = {0,1,2,3,4,5,6,7,8,9,10,11,12,13};             // setup_inputs order
    const InIdx LB = {4,5,13,0,1,2,7,3,12,11,9,8,6,10};             // sorted pytree order
    long long s32[14], s64[14];
    for (int i = 0; i < 14; ++i) s32[i] = ((const int*)in_sizes)[i];

    auto valid = [](const long long* s, const InIdx& I) -> bool {
        long long T = s[I.Z];
        if (T < 1 || T > T_MAX) return false;
        if (s[I.S_e] <= 0 || s[I.S_i] <= 0) return false;
        if (s[I.S_e] % T || s[I.S_i] % T) return false;
        long long Ee = s[I.S_e] / T, Ei = s[I.S_i] / T;
        if (Ee < 1 || Ee > E_MAX || Ei < 1 || Ei > E_MAX) return false;
        return s[I.C_den] == SUB * SUB && s[I.C_se] == SUB * Ee && s[I.C_si] == SUB * Ei
            && s[I.Tau] == 2 * SUB && s[I.Del] == 2 * SUB && s[I.Wsyn] == 2 * SUB
            && s[I.Wsub] == SUB && s[I.Whist] == COS_N && s[I.Theta] == SUB
            && s[I.TauO] == 1 && s[I.Wout] == 1;
    };

    const long long* S = nullptr; const InIdx* I = nullptr;
    if      (valid(s32, LA)) { S = s32; I = &LA; }
    else if (valid(s32, LB)) { S = s32; I = &LB; }
    else {
        for (int i = 0; i < 14; ++i) s64[i] = ((const long long*)in_sizes)[i];
        if      (valid(s64, LA)) { S = s64; I = &LA; }
        else if (valid(s64, LB)) { S = s64; I = &LB; }
    }
    if (!S) {   // marker B: sizes indecipherable (error ~4.24e+01)
        hipMemsetAsync(d_out, 0x41, markbytes, stream);
        hipMemsetAsync(d_out, 0x41, markbytes, 0);
        return;
    }

    const int T   = (int)S[I->Z];
    const int E_e = (int)(S[I->S_e] / T);
    const int E_i = (int)(S[I->S_i] / T);

    if (out_size != 2 * T + (2 * SUB + 1) * T_NO) {  // marker C: output layout (error ~7.86e+01)
        hipMemsetAsync(d_out, 0xC1, markbytes, stream);
        hipMemsetAsync(d_out, 0xC1, markbytes, 0);
        return;
    }

    const void* S_e    = d_in[I->S_e];
    const void* S_i    = d_in[I->S_i];
    const void* Z      = d_in[I->Z];
    const void* C_den  = d_in[I->C_den];
    const void* C_se   = d_in[I->C_se];
    const void* C_si   = d_in[I->C_si];
    const void* Tau    = d_in[I->Tau];
    const void* Del    = d_in[I->Del];
    const void* Wsyn   = d_in[I->Wsyn];
    const void* Wsub   = d_in[I->Wsub];
    const void* Whist  = d_in[I->Whist];
    const void* Theta  = d_in[I->Theta];
    const void* TauO   = d_in[I->TauO];
    const void* Wout   = d_in[I->Wout];

    // dtype detect (bf16 vs f32) from S_e bit patterns; then execution probe
    int nwords = (int)((S[I->S_e] / 2 < 65536) ? S[I->S_e] / 2 : 65536);
    k_detect<<<1, 256, 0, stream>>>((const unsigned int*)S_e, nwords);
    k_fill<<<(out_size + 255) / 256, 256, 0, stream>>>(d_out, out_size, 2.0f);
    if (hipGetLastError() != hipSuccess) {   // marker D: launch API error (error ~4.85e+01)
        hipMemsetAsync(d_out, 0x42, markbytes, stream);
        hipMemsetAsync(d_out, 0x42, markbytes, 0);
        return;
    }

    // ---- real pipeline -----------------------------------------------------
    int setup_work = E_e + E_i + 2 * SUB * T_NO + 2 * T_NO;
    k_setup<<<(setup_work + 255) / 256, 256, 0, stream>>>(
        C_se, C_si, Tau, Del, Wsyn, Whist, TauO, Wout, d_out, T, E_e, E_i);
    k_project<<<(T + 3) / 4, 256, 0, stream>>>(S_e, S_i, T, E_e, E_i);
    k_conv<<<((size_t)T * SUB + 255) / 256, 256, 0, stream>>>(T);
    int tb = (T + 255) / 256;
    k_tree<<<tb, 256, 0, stream>>>(Z, C_den, Wsub, Theta, d_out, T);
    k_vout<<<tb, 256, 0, stream>>>(d_out, T);

    if (hipGetLastError() != hipSuccess) {   // marker E: pipeline launch error (error ~1.95e+02)
        hipMemsetAsync(d_out, 0x43, markbytes, stream);
        hipMemsetAsync(d_out, 0x43, markbytes, 0);
    }
}

// Round 6
// 648.236 us; speedup vs baseline: 1.4610x; 1.4610x over previous
//
#include <hip/hip_runtime.h>
#include <hip/hip_bf16.h>
#include <stdint.h>

#define T_NO 200
#define COS_N 17
#define SUB 32
#define T_MAX 40000
#define E_MAX 4096
#define PI_F 3.14159265358979323846f
#define HALF_PI_F 1.57079632679489662f

// ---- module-scope scratch (no dependence on d_ws / ws_size) ---------------
__device__ float g_syn_e[(size_t)T_MAX * SUB];
__device__ float g_syn_i[(size_t)T_MAX * SUB];
__device__ float g_syn_f[(size_t)T_MAX * SUB];
__device__ float g_ektT[T_NO * SUB];   // tau-major: [tau][sub]
__device__ float g_iktT[T_NO * SUB];
__device__ float g_hk[T_NO];
__device__ float g_ok[T_NO];
__device__ int   g_map_e[E_MAX];
__device__ float g_wgt_e[E_MAX];
__device__ int   g_map_i[E_MAX];
__device__ float g_wgt_i[E_MAX];
__device__ int   g_dtype;              // 0 = float32, 1 = bfloat16 (set per call)

// ---- dtype-dispatching load/store ----------------------------------------
__device__ __forceinline__ float ldx(const void* p, size_t i, int dt) {
    if (dt) return __bfloat162float(((const __hip_bfloat16*)p)[i]);
    return ((const float*)p)[i];
}
__device__ __forceinline__ void stx(void* p, size_t i, float v, int dt) {
    if (dt) ((__hip_bfloat16*)p)[i] = __float2bfloat16(v);
    else    ((float*)p)[i] = v;
}
__device__ __forceinline__ float bfbits2f(unsigned b) { return __uint_as_float(b << 16); }

// ---------------------------------------------------------------------------
// D0: dtype detect from S_e bit patterns. f32 spike words: {0, 0x3F800000}.
// bf16 pairs also yield 0x00003F80 / 0x3F803F80. 8192 words is plenty at 2%.
// ---------------------------------------------------------------------------
__global__ void k_detect(const unsigned int* w, int nwords)
{
    __shared__ int flag;
    if (threadIdx.x == 0) flag = 0;
    __syncthreads();
    for (int i = threadIdx.x; i < nwords; i += 256) {
        unsigned v = w[i];
        if (v == 0x00003F80u || v == 0x3F803F80u) flag = 1;
    }
    __syncthreads();
    if (threadIdx.x == 0) g_dtype = flag;
}

// ---------------------------------------------------------------------------
// K1: setup — column->subunit maps, e/i alpha kernels (tau-major), history
// kernel (cos basis), output kernel; writes out_filters at element 2*T.
// ---------------------------------------------------------------------------
__global__ void k_setup(
    const void* C_se, const void* C_si, const void* Tau_syn, const void* Delta_syn,
    const void* W_syn, const void* W_hist, const void* Tau_out, const void* W_out,
    void* out, int T, int E_e, int E_i)
{
    int dt = g_dtype;
    size_t fbase = 2 * (size_t)T;      // element offset of out_filters
    int tid = blockIdx.x * 256 + threadIdx.x;

    if (tid < E_e) {
        int e = tid, m = 0; float w = 0.f;
        for (int s = 0; s < SUB; ++s) {
            float c = ldx(C_se, (size_t)s * E_e + e, dt);
            if (c != 0.f) { m = s; w = c; }
        }
        g_map_e[e] = m; g_wgt_e[e] = w;
        return;
    }
    tid -= E_e;
    if (tid < E_i) {
        int e = tid, m = 0; float w = 0.f;
        for (int s = 0; s < SUB; ++s) {
            float c = ldx(C_si, (size_t)s * E_i + e, dt);
            if (c != 0.f) { m = s; w = c; }
        }
        g_map_i[e] = m; g_wgt_i[e] = w;
        return;
    }
    tid -= E_i;
    if (tid < SUB * T_NO) {            // e_kern
        int s = tid / T_NO, t = tid % T_NO;
        float delta = expf(ldx(Delta_syn, s * 2 + 0, dt));
        float tau   = expf(ldx(Tau_syn,   s * 2 + 0, dt));
        float w     = expf(ldx(W_syn,     s * 2 + 0, dt));
        float te = fmaxf((float)t - delta, 0.f) / tau;
        float v = te * expf(-te) * w;
        g_ektT[t * SUB + s] = v;
        stx(out, fbase + (size_t)s * T_NO + t, v, dt);
        return;
    }
    tid -= SUB * T_NO;
    if (tid < SUB * T_NO) {            // i_kern
        int s = tid / T_NO, t = tid % T_NO;
        float delta = expf(ldx(Delta_syn, s * 2 + 1, dt));
        float tau   = expf(ldx(Tau_syn,   s * 2 + 1, dt));
        float w     = expf(ldx(W_syn,     s * 2 + 1, dt));
        float ti = fmaxf((float)t - delta, 0.f) / tau;
        float v = -ti * expf(-ti) * w;
        g_iktT[t * SUB + s] = v;
        stx(out, fbase + (size_t)SUB * T_NO + (size_t)s * T_NO + t, v, dt);
        return;
    }
    tid -= SUB * T_NO;
    if (tid < T_NO) {                  // hist_kern = -(exp(W_hist) @ cos_basis)
        int t = tid;
        float raw = 4.0f * logf((float)t + 1.0f);
        float acc = 0.f;
        for (int n = 0; n < COS_N; ++n) {
            float phi = HALF_PI_F * (float)n;
            float d = raw - phi;
            float b = (raw >= phi - PI_F && raw <= phi + PI_F) ? (0.5f * cosf(d) + 0.5f) : 0.f;
            acc += expf(ldx(W_hist, n, dt)) * b;
        }
        float v = -acc;
        g_hk[t] = v;
        stx(out, fbase + 2 * (size_t)SUB * T_NO + t, v, dt);
        return;
    }
    tid -= T_NO;
    if (tid < T_NO) {                  // out_kern (internal only)
        float tau = expf(ldx(Tau_out, 0, dt));
        float w   = expf(ldx(W_out, 0, dt));
        float tt = (float)tid / tau;
        g_ok[tid] = tt * expf(-tt) * w;
    }
}

// ---------------------------------------------------------------------------
// K2: spike projection. One wave per time row; 16B vector loads (8 bf16 or
// 4 f32 per lane) with packed-zero fast skip; LDS atomicAdd into 32 buckets
// only on nonzero (2% dense) entries.
// ---------------------------------------------------------------------------
__device__ __forceinline__ void project_row(
    const void* rowv, int E, int dt,
    const int* __restrict__ map, const float* __restrict__ wgt,
    float* __restrict__ bucket, int lane)
{
    size_t rowbytes = (size_t)E * (dt ? 2 : 4);
    bool vec_ok = ((((uintptr_t)rowv) & 15) == 0) && ((rowbytes & 15) == 0);
    if (vec_ok) {
        const uint4* rv = (const uint4*)rowv;
        if (dt) {                        // bf16: 8 elems / 16B
            int nv = E >> 3;
            for (int k = lane; k < nv; k += 64) {
                uint4 p = rv[k];
                if (p.x | p.y | p.z | p.w) {
                    unsigned vv[4] = {p.x, p.y, p.z, p.w};
                    int base = k * 8;
#pragma unroll
                    for (int q = 0; q < 4; ++q) {
                        unsigned lo = vv[q] & 0xFFFFu, hi = vv[q] >> 16;
                        if (lo) { int c = base + 2 * q;     atomicAdd(&bucket[map[c]], bfbits2f(lo) * wgt[c]); }
                        if (hi) { int c = base + 2 * q + 1; atomicAdd(&bucket[map[c]], bfbits2f(hi) * wgt[c]); }
                    }
                }
            }
            for (int idx = ((E >> 3) << 3) + lane; idx < E; idx += 64) {
                float v = ldx(rowv, idx, dt);
                if (v != 0.f) atomicAdd(&bucket[map[idx]], v * wgt[idx]);
            }
        } else {                         // f32: 4 elems / 16B
            int nv = E >> 2;
            for (int k = lane; k < nv; k += 64) {
                uint4 p = rv[k];
                if (p.x | p.y | p.z | p.w) {
                    unsigned vv[4] = {p.x, p.y, p.z, p.w};
                    int base = k * 4;
#pragma unroll
                    for (int q = 0; q < 4; ++q)
                        if (vv[q]) { int c = base + q; atomicAdd(&bucket[map[c]], __uint_as_float(vv[q]) * wgt[c]); }
                }
            }
            for (int idx = ((E >> 2) << 2) + lane; idx < E; idx += 64) {
                float v = ldx(rowv, idx, dt);
                if (v != 0.f) atomicAdd(&bucket[map[idx]], v * wgt[idx]);
            }
        }
    } else {
        for (int idx = lane; idx < E; idx += 64) {
            float v = ldx(rowv, idx, dt);
            if (v != 0.f) atomicAdd(&bucket[map[idx]], v * wgt[idx]);
        }
    }
}

__global__ __launch_bounds__(256) void k_project(
    const void* Se, const void* Si, int T, int E_e, int E_i)
{
    __shared__ float bE[4 * SUB];
    __shared__ float bI[4 * SUB];
    int dt = g_dtype;
    int tid = threadIdx.x;
    if (tid < 128) bE[tid] = 0.f; else bI[tid - 128] = 0.f;
    __syncthreads();

    int wid = tid >> 6, lane = tid & 63;
    int t = blockIdx.x * 4 + wid;
    if (t < T) {
        const char* rowE = (const char*)Se + (size_t)t * E_e * (dt ? 2 : 4);
        const char* rowI = (const char*)Si + (size_t)t * E_i * (dt ? 2 : 4);
        project_row(rowE, E_e, dt, g_map_e, g_wgt_e, &bE[wid * SUB], lane);
        project_row(rowI, E_i, dt, g_map_i, g_wgt_i, &bI[wid * SUB], lane);
    }
    __syncthreads();
    if (t < T) {
        if (lane < SUB) g_syn_e[(size_t)t * SUB + lane] = bE[wid * SUB + lane];
        else            g_syn_i[(size_t)t * SUB + (lane - SUB)] = bI[wid * SUB + (lane - SUB)];
    }
}

// ---------------------------------------------------------------------------
// K3: depthwise causal conv, register-tiled: thread = (subunit s, 8 consecutive
// t). 8-deep sliding window over syn rows; 8 MACs per row-load instead of 1.
//   syn_f[t,s] = sum_tau ek[tau,s]*syn_e[t-1-tau,s] + ik[tau,s]*syn_i[t-1-tau,s]
// ---------------------------------------------------------------------------
__global__ __launch_bounds__(256) void k_conv(int T)
{
    int s = threadIdx.x & 31;
    int g = threadIdx.x >> 5;
    int t0 = blockIdx.x * 64 + g * 8;

    float acc[8], wE[8], wI[8];
#pragma unroll
    for (int j = 0; j < 8; ++j) acc[j] = 0.f;
#pragma unroll
    for (int j = 0; j < 8; ++j) {
        int r = t0 + j - 1;
        bool ok = (r >= 0) && (r < T);
        wE[j] = ok ? g_syn_e[(size_t)r * SUB + s] : 0.f;
        wI[j] = ok ? g_syn_i[(size_t)r * SUB + s] : 0.f;
    }
#pragma unroll 8
    for (int tau = 0; tau < T_NO; ++tau) {
        float ek = g_ektT[tau * SUB + s];
        float ik = g_iktT[tau * SUB + s];
#pragma unroll
        for (int j = 0; j < 8; ++j) acc[j] += ek * wE[j] + ik * wI[j];
#pragma unroll
        for (int j = 7; j >= 1; --j) { wE[j] = wE[j - 1]; wI[j] = wI[j - 1]; }
        int r = t0 - 2 - tau;
        bool ok = (r >= 0);
        wE[0] = ok ? g_syn_e[(size_t)r * SUB + s] : 0.f;
        wI[0] = ok ? g_syn_i[(size_t)r * SUB + s] : 0.f;
    }
#pragma unroll
    for (int j = 0; j < 8; ++j) {
        int t = t0 + j;
        if (t < T) g_syn_f[(size_t)t * SUB + s] = acc[j];
    }
}

// ---------------------------------------------------------------------------
// K4: history conv on observed Z + sequential tree walk (full C_den*exp(W_sub),
// scatter form matching the ref's descending-idx loop) + heaviside step.
// Writes Z_out at element offset T of out.
// ---------------------------------------------------------------------------
__global__ __launch_bounds__(256) void k_tree(
    const void* Z, const void* C_den, const void* W_sub,
    const void* Theta, void* out, int T)
{
    __shared__ float s_hk[T_NO];
    __shared__ float s_C[SUB * SUB];   // C_den[p][k] * exp(W_sub[k])
    __shared__ float s_th[SUB];
    int dt = g_dtype;
    int tid = threadIdx.x;
    for (int i = tid; i < T_NO; i += 256) s_hk[i] = g_hk[i];
    for (int i = tid; i < SUB * SUB; i += 256) {
        int p = i >> 5, k = i & 31;
        s_C[i] = ldx(C_den, p * SUB + k, dt) * expf(ldx(W_sub, k, dt));
    }
    if (tid < SUB) s_th[tid] = ldx(Theta, tid, dt);
    __syncthreads();

    int t = blockIdx.x * 256 + tid;
    if (t >= T) return;

    float h = 0.f;                     // sum_tau hk[tau] * Z[t-1-tau]
    if (t >= T_NO) {
#pragma unroll 8
        for (int tau = 0; tau < T_NO; ++tau)
            h += s_hk[tau] * ldx(Z, t - 1 - tau, dt);
    } else {
        for (int tau = 0; tau < t; ++tau)
            h += s_hk[tau] * ldx(Z, t - 1 - tau, dt);
    }

    float a[SUB];
#pragma unroll
    for (int j = 0; j < SUB; ++j) a[j] = g_syn_f[(size_t)t * SUB + j] + s_th[j];
#pragma unroll
    for (int idx = SUB - 1; idx >= 1; --idx) {
        float v = tanhf(a[idx]);
#pragma unroll
        for (int p = 0; p < SUB; ++p)
            if (p < idx) a[p] += v * s_C[p * SUB + idx];
    }
    float zin = a[0] + h;
    stx(out, (size_t)T + t, (zin > 0.f ? 1.f : 0.f), dt);   // heaviside(x,0)
}

// ---------------------------------------------------------------------------
// K5: output alpha-kernel conv of Z_out (read back from out at offset T).
// ---------------------------------------------------------------------------
__global__ __launch_bounds__(256) void k_vout(void* out, int T)
{
    __shared__ float s_ok[T_NO];
    int dt = g_dtype;
    for (int i = threadIdx.x; i < T_NO; i += 256) s_ok[i] = g_ok[i];
    __syncthreads();
    int t = blockIdx.x * 256 + threadIdx.x;
    if (t >= T) return;
    float acc = 0.f;
    if (t >= T_NO) {
#pragma unroll 8
        for (int tau = 0; tau < T_NO; ++tau)
            acc += s_ok[tau] * ldx(out, (size_t)T + (t - 1 - tau), dt);
    } else {
        for (int tau = 0; tau < t; ++tau)
            acc += s_ok[tau] * ldx(out, (size_t)T + (t - 1 - tau), dt);
    }
    stx(out, t, acc, dt);
}

// ---------------------------------------------------------------------------
struct InIdx { int S_e, S_i, Z, C_den, C_se, C_si, Tau, Del, Wsyn, Wsub, Whist, Theta, TauO, Wout; };

extern "C" void kernel_launch(void* const* d_in, const int* in_sizes, int n_in,
                              void* d_out, int out_size, void* d_ws, size_t ws_size,
                              hipStream_t stream)
{
    (void)n_in; (void)d_ws; (void)ws_size;
    size_t markbytes = (size_t)out_size * 2;

    // ---- decode in_sizes: int32 vs int64, insertion vs sorted order --------
    const InIdx LA = {0,1,2,3,4,5,6,7,8,9,10,11,12,13};             // setup_inputs order
    const InIdx LB = {4,5,13,0,1,2,7,3,12,11,9,8,6,10};             // sorted pytree order
    long long s32[14], s64[14];
    for (int i = 0; i < 14; ++i) s32[i] = ((const int*)in_sizes)[i];

    auto valid = [](const long long* s, const InIdx& I) -> bool {
        long long T = s[I.Z];
        if (T < 1 || T > T_MAX) return false;
        if (s[I.S_e] <= 0 || s[I.S_i] <= 0) return false;
        if (s[I.S_e] % T || s[I.S_i] % T) return false;
        long long Ee = s[I.S_e] / T, Ei = s[I.S_i] / T;
        if (Ee < 1 || Ee > E_MAX || Ei < 1 || Ei > E_MAX) return false;
        return s[I.C_den] == SUB * SUB && s[I.C_se] == SUB * Ee && s[I.C_si] == SUB * Ei
            && s[I.Tau] == 2 * SUB && s[I.Del] == 2 * SUB && s[I.Wsyn] == 2 * SUB
            && s[I.Wsub] == SUB && s[I.Whist] == COS_N && s[I.Theta] == SUB
            && s[I.TauO] == 1 && s[I.Wout] == 1;
    };

    const long long* S = nullptr; const InIdx* I = nullptr;
    if      (valid(s32, LA)) { S = s32; I = &LA; }
    else if (valid(s32, LB)) { S = s32; I = &LB; }
    else {
        for (int i = 0; i < 14; ++i) s64[i] = ((const long long*)in_sizes)[i];
        if      (valid(s64, LA)) { S = s64; I = &LA; }
        else if (valid(s64, LB)) { S = s64; I = &LB; }
    }
    if (!S) { hipMemsetAsync(d_out, 0x41, markbytes, stream); return; }

    const int T   = (int)S[I->Z];
    const int E_e = (int)(S[I->S_e] / T);
    const int E_i = (int)(S[I->S_i] / T);
    if (out_size != 2 * T + (2 * SUB + 1) * T_NO) {
        hipMemsetAsync(d_out, 0xC1, markbytes, stream); return;
    }

    const void* S_e   = d_in[I->S_e];
    const void* S_i   = d_in[I->S_i];
    const void* Z     = d_in[I->Z];
    const void* C_den = d_in[I->C_den];
    const void* C_se  = d_in[I->C_se];
    const void* C_si  = d_in[I->C_si];
    const void* Tau   = d_in[I->Tau];
    const void* Del   = d_in[I->Del];
    const void* Wsyn  = d_in[I->Wsyn];
    const void* Wsub  = d_in[I->Wsub];
    const void* Whist = d_in[I->Whist];
    const void* Theta = d_in[I->Theta];
    const void* TauO  = d_in[I->TauO];
    const void* Wout  = d_in[I->Wout];

    // dtype detect (bf16 vs f32) from S_e bit patterns
    int nwords = (int)((S[I->S_e] / 2 < 8192) ? S[I->S_e] / 2 : 8192);
    k_detect<<<1, 256, 0, stream>>>((const unsigned int*)S_e, nwords);

    int setup_work = E_e + E_i + 2 * SUB * T_NO + 2 * T_NO;
    k_setup<<<(setup_work + 255) / 256, 256, 0, stream>>>(
        C_se, C_si, Tau, Del, Wsyn, Whist, TauO, Wout, d_out, T, E_e, E_i);

    k_project<<<(T + 3) / 4, 256, 0, stream>>>(S_e, S_i, T, E_e, E_i);

    k_conv<<<(T + 63) / 64, 256, 0, stream>>>(T);

    int tb = (T + 255) / 256;
    k_tree<<<tb, 256, 0, stream>>>(Z, C_den, Wsub, Theta, d_out, T);
    k_vout<<<tb, 256, 0, stream>>>(d_out, T);
}

// Round 8
// 618.547 us; speedup vs baseline: 1.5311x; 1.0480x over previous
//
#include <hip/hip_runtime.h>
#include <hip/hip_bf16.h>
#include <stdint.h>

#define T_NO 200
#define COS_N 17
#define SUB 32
#define T_MAX 40000
#define E_MAX 4096
#define PI_F 3.14159265358979323846f
#define HALF_PI_F 1.57079632679489662f

// ---- module-scope scratch (no dependence on d_ws / ws_size) ---------------
__device__ float g_syn_e[(size_t)T_MAX * SUB];
__device__ float g_syn_i[(size_t)T_MAX * SUB];
__device__ float g_syn_f[(size_t)T_MAX * SUB];
__device__ float g_ektT[T_NO * SUB];   // tau-major: [tau][sub]
__device__ float g_iktT[T_NO * SUB];
__device__ float g_hk[T_NO];
__device__ float g_ok[T_NO];
__device__ int   g_map_e[E_MAX];
__device__ float g_wgt_e[E_MAX];
__device__ int   g_map_i[E_MAX];
__device__ float g_wgt_i[E_MAX];
__device__ int   g_dtype;              // 0 = float32, 1 = bfloat16 (set per call)

// ---- dtype-dispatching load/store ----------------------------------------
__device__ __forceinline__ float ldx(const void* p, size_t i, int dt) {
    if (dt) return __bfloat162float(((const __hip_bfloat16*)p)[i]);
    return ((const float*)p)[i];
}
__device__ __forceinline__ void stx(void* p, size_t i, float v, int dt) {
    if (dt) ((__hip_bfloat16*)p)[i] = __float2bfloat16(v);
    else    ((float*)p)[i] = v;
}
__device__ __forceinline__ float bfbits2f(unsigned b) { return __uint_as_float(b << 16); }

// ---------------------------------------------------------------------------
// D0: dtype detect from S_e bit patterns. f32 spike words: {0, 0x3F800000}.
// bf16 pairs also yield 0x00003F80 / 0x3F803F80. 8192 words is plenty at 2%.
// ---------------------------------------------------------------------------
__global__ void k_detect(const unsigned int* w, int nwords)
{
    __shared__ int flag;
    if (threadIdx.x == 0) flag = 0;
    __syncthreads();
    for (int i = threadIdx.x; i < nwords; i += 256) {
        unsigned v = w[i];
        if (v == 0x00003F80u || v == 0x3F803F80u) flag = 1;
    }
    __syncthreads();
    if (threadIdx.x == 0) g_dtype = flag;
}

// ---------------------------------------------------------------------------
// K1: setup — column->subunit maps, e/i alpha kernels (tau-major), history
// kernel (cos basis), output kernel; writes out_filters at element 2*T.
// ---------------------------------------------------------------------------
__global__ void k_setup(
    const void* C_se, const void* C_si, const void* Tau_syn, const void* Delta_syn,
    const void* W_syn, const void* W_hist, const void* Tau_out, const void* W_out,
    void* out, int T, int E_e, int E_i)
{
    int dt = g_dtype;
    size_t fbase = 2 * (size_t)T;      // element offset of out_filters
    int tid = blockIdx.x * 256 + threadIdx.x;

    if (tid < E_e) {
        int e = tid, m = 0; float w = 0.f;
        for (int s = 0; s < SUB; ++s) {
            float c = ldx(C_se, (size_t)s * E_e + e, dt);
            if (c != 0.f) { m = s; w = c; }
        }
        g_map_e[e] = m; g_wgt_e[e] = w;
        return;
    }
    tid -= E_e;
    if (tid < E_i) {
        int e = tid, m = 0; float w = 0.f;
        for (int s = 0; s < SUB; ++s) {
            float c = ldx(C_si, (size_t)s * E_i + e, dt);
            if (c != 0.f) { m = s; w = c; }
        }
        g_map_i[e] = m; g_wgt_i[e] = w;
        return;
    }
    tid -= E_i;
    if (tid < SUB * T_NO) {            // e_kern
        int s = tid / T_NO, t = tid % T_NO;
        float delta = expf(ldx(Delta_syn, s * 2 + 0, dt));
        float tau   = expf(ldx(Tau_syn,   s * 2 + 0, dt));
        float w     = expf(ldx(W_syn,     s * 2 + 0, dt));
        float te = fmaxf((float)t - delta, 0.f) / tau;
        float v = te * expf(-te) * w;
        g_ektT[t * SUB + s] = v;
        stx(out, fbase + (size_t)s * T_NO + t, v, dt);
        return;
    }
    tid -= SUB * T_NO;
    if (tid < SUB * T_NO) {            // i_kern
        int s = tid / T_NO, t = tid % T_NO;
        float delta = expf(ldx(Delta_syn, s * 2 + 1, dt));
        float tau   = expf(ldx(Tau_syn,   s * 2 + 1, dt));
        float w     = expf(ldx(W_syn,     s * 2 + 1, dt));
        float ti = fmaxf((float)t - delta, 0.f) / tau;
        float v = -ti * expf(-ti) * w;
        g_iktT[t * SUB + s] = v;
        stx(out, fbase + (size_t)SUB * T_NO + (size_t)s * T_NO + t, v, dt);
        return;
    }
    tid -= SUB * T_NO;
    if (tid < T_NO) {                  // hist_kern = -(exp(W_hist) @ cos_basis)
        int t = tid;
        float raw = 4.0f * logf((float)t + 1.0f);
        float acc = 0.f;
        for (int n = 0; n < COS_N; ++n) {
            float phi = HALF_PI_F * (float)n;
            float d = raw - phi;
            float b = (raw >= phi - PI_F && raw <= phi + PI_F) ? (0.5f * cosf(d) + 0.5f) : 0.f;
            acc += expf(ldx(W_hist, n, dt)) * b;
        }
        float v = -acc;
        g_hk[t] = v;
        stx(out, fbase + 2 * (size_t)SUB * T_NO + t, v, dt);
        return;
    }
    tid -= T_NO;
    if (tid < T_NO) {                  // out_kern (internal only)
        float tau = expf(ldx(Tau_out, 0, dt));
        float w   = expf(ldx(W_out, 0, dt));
        float tt = (float)tid / tau;
        g_ok[tid] = tt * expf(-tt) * w;
    }
}

// ---------------------------------------------------------------------------
// K2: spike projection. One wave per time row; 16B vector loads (8 bf16 or
// 4 f32 per lane) with packed-zero fast skip; LDS atomicAdd into 32 buckets
// only on nonzero (2% dense) entries.
// ---------------------------------------------------------------------------
__device__ __forceinline__ void project_row(
    const void* rowv, int E, int dt,
    const int* __restrict__ map, const float* __restrict__ wgt,
    float* __restrict__ bucket, int lane)
{
    size_t rowbytes = (size_t)E * (dt ? 2 : 4);
    bool vec_ok = ((((uintptr_t)rowv) & 15) == 0) && ((rowbytes & 15) == 0);
    if (vec_ok) {
        const uint4* rv = (const uint4*)rowv;
        if (dt) {                        // bf16: 8 elems / 16B
            int nv = E >> 3;
            for (int k = lane; k < nv; k += 64) {
                uint4 p = rv[k];
                if (p.x | p.y | p.z | p.w) {
                    unsigned vv[4] = {p.x, p.y, p.z, p.w};
                    int base = k * 8;
#pragma unroll
                    for (int q = 0; q < 4; ++q) {
                        unsigned lo = vv[q] & 0xFFFFu, hi = vv[q] >> 16;
                        if (lo) { int c = base + 2 * q;     atomicAdd(&bucket[map[c]], bfbits2f(lo) * wgt[c]); }
                        if (hi) { int c = base + 2 * q + 1; atomicAdd(&bucket[map[c]], bfbits2f(hi) * wgt[c]); }
                    }
                }
            }
            for (int idx = ((E >> 3) << 3) + lane; idx < E; idx += 64) {
                float v = ldx(rowv, idx, dt);
                if (v != 0.f) atomicAdd(&bucket[map[idx]], v * wgt[idx]);
            }
        } else {                         // f32: 4 elems / 16B
            int nv = E >> 2;
            for (int k = lane; k < nv; k += 64) {
                uint4 p = rv[k];
                if (p.x | p.y | p.z | p.w) {
                    unsigned vv[4] = {p.x, p.y, p.z, p.w};
                    int base = k * 4;
#pragma unroll
                    for (int q = 0; q < 4; ++q)
                        if (vv[q]) { int c = base + q; atomicAdd(&bucket[map[c]], __uint_as_float(vv[q]) * wgt[c]); }
                }
            }
            for (int idx = ((E >> 2) << 2) + lane; idx < E; idx += 64) {
                float v = ldx(rowv, idx, dt);
                if (v != 0.f) atomicAdd(&bucket[map[idx]], v * wgt[idx]);
            }
        }
    } else {
        for (int idx = lane; idx < E; idx += 64) {
            float v = ldx(rowv, idx, dt);
            if (v != 0.f) atomicAdd(&bucket[map[idx]], v * wgt[idx]);
        }
    }
}

__global__ __launch_bounds__(256) void k_project(
    const void* Se, const void* Si, int T, int E_e, int E_i)
{
    __shared__ float bE[4 * SUB];
    __shared__ float bI[4 * SUB];
    int dt = g_dtype;
    int tid = threadIdx.x;
    if (tid < 128) bE[tid] = 0.f; else bI[tid - 128] = 0.f;
    __syncthreads();

    int wid = tid >> 6, lane = tid & 63;
    int t = blockIdx.x * 4 + wid;
    if (t < T) {
        const char* rowE = (const char*)Se + (size_t)t * E_e * (dt ? 2 : 4);
        const char* rowI = (const char*)Si + (size_t)t * E_i * (dt ? 2 : 4);
        project_row(rowE, E_e, dt, g_map_e, g_wgt_e, &bE[wid * SUB], lane);
        project_row(rowI, E_i, dt, g_map_i, g_wgt_i, &bI[wid * SUB], lane);
    }
    __syncthreads();
    if (t < T) {
        if (lane < SUB) g_syn_e[(size_t)t * SUB + lane] = bE[wid * SUB + lane];
        else            g_syn_i[(size_t)t * SUB + (lane - SUB)] = bI[wid * SUB + (lane - SUB)];
    }
}

// ---------------------------------------------------------------------------
// K3: depthwise causal conv, register-tiled: thread = (subunit s, 8 consecutive
// t). 8-deep sliding window over syn rows; 8 MACs per row-load instead of 1.
//   syn_f[t,s] = sum_tau ek[tau,s]*syn_e[t-1-tau,s] + ik[tau,s]*syn_i[t-1-tau,s]
// ---------------------------------------------------------------------------
__global__ __launch_bounds__(256) void k_conv(int T)
{
    int s = threadIdx.x & 31;
    int g = threadIdx.x >> 5;
    int t0 = blockIdx.x * 64 + g * 8;

    float acc[8], wE[8], wI[8];
#pragma unroll
    for (int j = 0; j < 8; ++j) acc[j] = 0.f;
#pragma unroll
    for (int j = 0; j < 8; ++j) {
        int r = t0 + j - 1;
        bool ok = (r >= 0) && (r < T);
        wE[j] = ok ? g_syn_e[(size_t)r * SUB + s] : 0.f;
        wI[j] = ok ? g_syn_i[(size_t)r * SUB + s] : 0.f;
    }
#pragma unroll 8
    for (int tau = 0; tau < T_NO; ++tau) {
        float ek = g_ektT[tau * SUB + s];
        float ik = g_iktT[tau * SUB + s];
#pragma unroll
        for (int j = 0; j < 8; ++j) acc[j] += ek * wE[j] + ik * wI[j];
#pragma unroll
        for (int j = 7; j >= 1; --j) { wE[j] = wE[j - 1]; wI[j] = wI[j - 1]; }
        int r = t0 - 2 - tau;
        bool ok = (r >= 0);
        wE[0] = ok ? g_syn_e[(size_t)r * SUB + s] : 0.f;
        wI[0] = ok ? g_syn_i[(size_t)r * SUB + s] : 0.f;
    }
#pragma unroll
    for (int j = 0; j < 8; ++j) {
        int t = t0 + j;
        if (t < T) g_syn_f[(size_t)t * SUB + s] = acc[j];
    }
}

// ---------------------------------------------------------------------------
// K4: history conv on observed Z (LDS-staged, zero-padded window) + tree walk
// (full C_den*exp(W_sub), scatter form matching the ref's descending-idx loop)
// + heaviside step. Writes Z_out at element offset T of out.
// ---------------------------------------------------------------------------
__global__ __launch_bounds__(256) void k_tree(
    const void* Z, const void* C_den, const void* W_sub,
    const void* Theta, void* out, int T)
{
    __shared__ float s_hk[T_NO];
    __shared__ float s_C[SUB * SUB];   // C_den[p][k] * exp(W_sub[k])
    __shared__ float s_th[SUB];
    __shared__ float s_Z[256 + T_NO];  // Z[t0-200 .. t0+255], zero-padded
    int dt = g_dtype;
    int tid = threadIdx.x;
    int t0 = blockIdx.x * 256;
    for (int i = tid; i < T_NO; i += 256) s_hk[i] = g_hk[i];
    for (int i = tid; i < SUB * SUB; i += 256) {
        int p = i >> 5, k = i & 31;
        s_C[i] = ldx(C_den, p * SUB + k, dt) * expf(ldx(W_sub, k, dt));
    }
    if (tid < SUB) s_th[tid] = ldx(Theta, tid, dt);
    for (int i = tid; i < 256 + T_NO; i += 256) {
        int r = t0 - T_NO + i;
        s_Z[i] = (r >= 0 && r < T) ? ldx(Z, r, dt) : 0.f;
    }
    __syncthreads();

    int t = t0 + tid;
    if (t >= T) return;

    // h = sum_tau hk[tau]*Z[t-1-tau]; s_Z index of global r is r - t0 + 200
    float h = 0.f;
#pragma unroll 8
    for (int tau = 0; tau < T_NO; ++tau)
        h += s_hk[tau] * s_Z[tid + T_NO - 1 - tau];

    float a[SUB];
#pragma unroll
    for (int j = 0; j < SUB; ++j) a[j] = g_syn_f[(size_t)t * SUB + j] + s_th[j];
#pragma unroll
    for (int idx = SUB - 1; idx >= 1; --idx) {
        float v = tanhf(a[idx]);
#pragma unroll
        for (int p = 0; p < SUB; ++p)
            if (p < idx) a[p] += v * s_C[p * SUB + idx];
    }
    float zin = a[0] + h;
    stx(out, (size_t)T + t, (zin > 0.f ? 1.f : 0.f), dt);   // heaviside(x,0)
}

// ---------------------------------------------------------------------------
// K5: output alpha-kernel conv of Z_out (LDS-staged, zero-padded window).
// ---------------------------------------------------------------------------
__global__ __launch_bounds__(256) void k_vout(void* out, int T)
{
    __shared__ float s_ok[T_NO];
    __shared__ float s_Z[256 + T_NO];
    int dt = g_dtype;
    int tid = threadIdx.x;
    int t0 = blockIdx.x * 256;
    for (int i = tid; i < T_NO; i += 256) s_ok[i] = g_ok[i];
    for (int i = tid; i < 256 + T_NO; i += 256) {
        int r = t0 - T_NO + i;
        s_Z[i] = (r >= 0 && r < T) ? ldx(out, (size_t)T + r, dt) : 0.f;
    }
    __syncthreads();

    int t = t0 + tid;
    if (t >= T) return;
    float acc = 0.f;
#pragma unroll 8
    for (int tau = 0; tau < T_NO; ++tau)
        acc += s_ok[tau] * s_Z[tid + T_NO - 1 - tau];
    stx(out, t, acc, dt);
}

// ---------------------------------------------------------------------------
struct InIdx { int S_e, S_i, Z, C_den, C_se, C_si, Tau, Del, Wsyn, Wsub, Whist, Theta, TauO, Wout; };

extern "C" void kernel_launch(void* const* d_in, const int* in_sizes, int n_in,
                              void* d_out, int out_size, void* d_ws, size_t ws_size,
                              hipStream_t stream)
{
    (void)n_in; (void)d_ws; (void)ws_size;
    size_t markbytes = (size_t)out_size * 2;

    // ---- decode in_sizes: int32 vs int64, insertion vs sorted order --------
    const InIdx LA = {0,1,2,3,4,5,6,7,8,9,10,11,12,13};             // setup_inputs order
    const InIdx LB = {4,5,13,0,1,2,7,3,12,11,9,8,6,10};             // sorted pytree order
    long long s32[14], s64[14];
    for (int i = 0; i < 14; ++i) s32[i] = ((const int*)in_sizes)[i];

    auto valid = [](const long long* s, const InIdx& I) -> bool {
        long long T = s[I.Z];
        if (T < 1 || T > T_MAX) return false;
        if (s[I.S_e] <= 0 || s[I.S_i] <= 0) return false;
        if (s[I.S_e] % T || s[I.S_i] % T) return false;
        long long Ee = s[I.S_e] / T, Ei = s[I.S_i] / T;
        if (Ee < 1 || Ee > E_MAX || Ei < 1 || Ei > E_MAX) return false;
        return s[I.C_den] == SUB * SUB && s[I.C_se] == SUB * Ee && s[I.C_si] == SUB * Ei
            && s[I.Tau] == 2 * SUB && s[I.Del] == 2 * SUB && s[I.Wsyn] == 2 * SUB
            && s[I.Wsub] == SUB && s[I.Whist] == COS_N && s[I.Theta] == SUB
            && s[I.TauO] == 1 && s[I.Wout] == 1;
    };

    const long long* S = nullptr; const InIdx* I = nullptr;
    if      (valid(s32, LA)) { S = s32; I = &LA; }
    else if (valid(s32, LB)) { S = s32; I = &LB; }
    else {
        for (int i = 0; i < 14; ++i) s64[i] = ((const long long*)in_sizes)[i];
        if      (valid(s64, LA)) { S = s64; I = &LA; }
        else if (valid(s64, LB)) { S = s64; I = &LB; }
    }
    if (!S) { hipMemsetAsync(d_out, 0x41, markbytes, stream); return; }

    const int T   = (int)S[I->Z];
    const int E_e = (int)(S[I->S_e] / T);
    const int E_i = (int)(S[I->S_i] / T);
    if (out_size != 2 * T + (2 * SUB + 1) * T_NO) {
        hipMemsetAsync(d_out, 0xC1, markbytes, stream); return;
    }

    const void* S_e   = d_in[I->S_e];
    const void* S_i   = d_in[I->S_i];
    const void* Z     = d_in[I->Z];
    const void* C_den = d_in[I->C_den];
    const void* C_se  = d_in[I->C_se];
    const void* C_si  = d_in[I->C_si];
    const void* Tau   = d_in[I->Tau];
    const void* Del   = d_in[I->Del];
    const void* Wsyn  = d_in[I->Wsyn];
    const void* Wsub  = d_in[I->Wsub];
    const void* Whist = d_in[I->Whist];
    const void* Theta = d_in[I->Theta];
    const void* TauO  = d_in[I->TauO];
    const void* Wout  = d_in[I->Wout];

    // dtype detect (bf16 vs f32) from S_e bit patterns
    int nwords = (int)((S[I->S_e] / 2 < 8192) ? S[I->S_e] / 2 : 8192);
    k_detect<<<1, 256, 0, stream>>>((const unsigned int*)S_e, nwords);

    int setup_work = E_e + E_i + 2 * SUB * T_NO + 2 * T_NO;
    k_setup<<<(setup_work + 255) / 256, 256, 0, stream>>>(
        C_se, C_si, Tau, Del, Wsyn, Whist, TauO, Wout, d_out, T, E_e, E_i);

    k_project<<<(T + 3) / 4, 256, 0, stream>>>(S_e, S_i, T, E_e, E_i);

    k_conv<<<(T + 63) / 64, 256, 0, stream>>>(T);

    int tb = (T + 255) / 256;
    k_tree<<<tb, 256, 0, stream>>>(Z, C_den, Wsub, Theta, d_out, T);
    k_vout<<<tb, 256, 0, stream>>>(d_out, T);
}